// Round 7
// baseline (369.666 us; speedup 1.0000x reference)
//
#include <hip/hip_runtime.h>

#define N_NODES 100000
#define N_EDGES 1600000
#define F_IN 256
#define F_HID 128
#define F_OUT 32
#define NBUCK 391           // ceil(100000/256) buckets of 256 node ids
#define BIN_BLOCKS 512
#define EDGES_PER_BIN 3125  // 512*3125 = 1,600,000
#define G1_BLOCKS 1563      // ceil(100000/64) 64-row gemm1 tiles

typedef unsigned short ushort_t;
typedef unsigned int uint_t;

using short8  = __attribute__((ext_vector_type(8))) short;
using floatx4 = __attribute__((ext_vector_type(4))) float;

__device__ __forceinline__ ushort_t f2bf(float f) {
    uint_t u = __float_as_uint(f);
    u += 0x7fff + ((u >> 16) & 1);  // RNE
    return (ushort_t)(u >> 16);
}
__device__ __forceinline__ float bf_lo(uint_t u) { return __uint_as_float(u << 16); }
__device__ __forceinline__ float bf_hi(uint_t u) { return __uint_as_float(u & 0xffff0000u); }
// pack hi16(b):hi16(a) into one uint via v_perm_b32 (truncating bf16 x2, 1 instr)
__device__ __forceinline__ uint_t bfpack_trunc(float a, float b) {
    return __builtin_amdgcn_perm(__float_as_uint(b), __float_as_uint(a), 0x07060302u);
}

// ---------------- CSR pass 1 (blocks 0..511) + weight transpose (blocks 512..543) ----------------
__global__ __launch_bounds__(256) void histwt_kernel(const int* __restrict__ ei,
                                                     int* __restrict__ bucket_cnt,
                                                     const float* __restrict__ W1,
                                                     const float* __restrict__ W2,
                                                     ushort_t* __restrict__ W1T,
                                                     ushort_t* __restrict__ W2T) {
    __shared__ int h[NBUCK];
    if (blockIdx.x < BIN_BLOCKS) {
        for (int i = threadIdx.x; i < NBUCK; i += 256) h[i] = 0;
        __syncthreads();
        int gid = blockIdx.x * 256 + threadIdx.x;
        for (int e = gid; e < N_EDGES; e += BIN_BLOCKS * 256)
            atomicAdd(&h[ei[N_EDGES + e] >> 8], 1);
        __syncthreads();
        for (int i = threadIdx.x; i < NBUCK; i += 256) {
            int c = h[i];
            if (c) atomicAdd(&bucket_cnt[i], c);
        }
    } else {
        int t = (blockIdx.x - BIN_BLOCKS) * 256 + threadIdx.x;  // 0..8191
#pragma unroll
        for (int j = 0; j < 4; j++) {
            int e = j * 8192 + t;                // e = n*256 + k
            int n = e >> 8, k = e & 255;
            W1T[e] = f2bf(W1[k * F_HID + n]);
        }
        if (t < 4096) {
            int n = t >> 7, k = t & 127;
            W2T[t] = f2bf(W2[k * F_OUT + n]);
        }
    }
}

// ---------------- CSR build: scan bucket counts ----------------
__global__ __launch_bounds__(512) void scan_kernel(const int* __restrict__ bucket_cnt,
                                                   int* __restrict__ bucket_base,
                                                   int* __restrict__ bucket_cursor,
                                                   int* __restrict__ offs) {
    __shared__ int s[512];
    int t = threadIdx.x;
    int own = (t < NBUCK) ? bucket_cnt[t] : 0;
    s[t] = own;
    __syncthreads();
    for (int off = 1; off < 512; off <<= 1) {
        int v = (t >= off) ? s[t - off] : 0;
        __syncthreads();
        s[t] += v;
        __syncthreads();
    }
    if (t < NBUCK) {
        int ex = s[t] - own;
        bucket_base[t] = ex;
        bucket_cursor[t] = ex;
    }
    if (t == 0) {
        bucket_base[NBUCK] = N_EDGES;
        offs[N_NODES] = N_EDGES;
    }
}

// ---------------- fused: CSR bin (blocks 0..511) + GEMM1 (blocks 512..2074) ----------------
// bin part: bin edges into bucket regions (3.1 KB smem, the kernel's entire LDS footprint).
// gemm1 part: h0 = bf16(x @ W1), 256 threads / 4 waves, 64-row tile, NO LDS —
//   B fragments are read straight from W1T global (64 KB, identical for every block ->
//   L2-resident; staging it per-block cost 66 KB LDS and capped occupancy at 2 blocks/CU).
//   Output column-split: cols 0..63 -> h0a[N][64], 64..127 -> h0b[N][64].
__global__ __launch_bounds__(256) void bin_gemm1_kernel(const int* __restrict__ ei,
                                                        int* __restrict__ bucket_cursor,
                                                        int2* __restrict__ binned,
                                                        const float* __restrict__ x,
                                                        const ushort_t* __restrict__ W1T,
                                                        ushort_t* __restrict__ h0a,
                                                        ushort_t* __restrict__ h0b) {
    __shared__ int h[NBUCK];
    __shared__ int base[NBUCK];
    const int tid = threadIdx.x;
    if (blockIdx.x < BIN_BLOCKS) {
        const int beg = blockIdx.x * EDGES_PER_BIN;
        const int end = beg + EDGES_PER_BIN;
        for (int i = tid; i < NBUCK; i += 256) h[i] = 0;
        __syncthreads();
        for (int e = beg + tid; e < end; e += 256) atomicAdd(&h[ei[N_EDGES + e] >> 8], 1);
        __syncthreads();
        for (int i = tid; i < NBUCK; i += 256) {
            int c = h[i];
            base[i] = c ? atomicAdd(&bucket_cursor[i], c) : 0;
            h[i] = 0;
        }
        __syncthreads();
        for (int e = beg + tid; e < end; e += 256) {
            int s = ei[e], d = ei[N_EDGES + e];
            int bk = d >> 8;
            int p = base[bk] + atomicAdd(&h[bk], 1);
            binned[p] = make_int2(s, d);
        }
    } else {
        const int rbase = (blockIdx.x - BIN_BLOCKS) * 64;
        const int w = tid >> 6;        // wave 0..3
        const int lane = tid & 63;
        const int q = lane >> 4;       // quad 0..3
        const int nloc = lane & 15;    // 0..15

        const int rowA = rbase + w * 16 + nloc;
        const bool okA = rowA < N_NODES;
        const float* ap = x + (size_t)rowA * F_IN + q * 8;
        const ushort_t* bp = W1T + nloc * F_IN + q * 8;  // row nloc(+16t), k-chunk q

        floatx4 acc[8];
#pragma unroll
        for (int t = 0; t < 8; t++) acc[t] = (floatx4){0.f, 0.f, 0.f, 0.f};

#pragma unroll
        for (int k0 = 0; k0 < F_IN; k0 += 32) {
            float4 f0 = make_float4(0.f, 0.f, 0.f, 0.f);
            float4 f1 = make_float4(0.f, 0.f, 0.f, 0.f);
            if (okA) {
                f0 = *(const float4*)(ap + k0);
                f1 = *(const float4*)(ap + k0 + 4);
            }
            uint4 au;
            au.x = bfpack_trunc(f0.x, f0.y);
            au.y = bfpack_trunc(f0.z, f0.w);
            au.z = bfpack_trunc(f1.x, f1.y);
            au.w = bfpack_trunc(f1.z, f1.w);
            short8 a = *(short8*)&au;
#pragma unroll
            for (int t = 0; t < 8; t++) {
                short8 b = *(const short8*)(bp + (size_t)t * 16 * F_IN + k0);
                acc[t] = __builtin_amdgcn_mfma_f32_16x16x32_bf16(a, b, acc[t], 0, 0, 0);
            }
        }

        // D layout: col = lane&15 (n within tile), row = q*4 + reg
#pragma unroll
        for (int reg = 0; reg < 4; reg++) {
            int rowD = rbase + w * 16 + q * 4 + reg;
            if (rowD < N_NODES) {
                ushort_t* opA = h0a + (size_t)rowD * 64 + nloc;
                ushort_t* opB = h0b + (size_t)rowD * 64 + nloc;
#pragma unroll
                for (int t = 0; t < 4; t++) opA[t * 16] = f2bf(acc[t][reg]);
#pragma unroll
                for (int t = 4; t < 8; t++) opB[(t - 4) * 16] = f2bf(acc[t][reg]);
            }
        }
    }
}

// ---------------- CSR build, pass 3: per-bucket offs/dinv/deg/csr ----------------
__global__ __launch_bounds__(256) void build_kernel(const int2* __restrict__ binned,
                                                    const int* __restrict__ bucket_base,
                                                    int* __restrict__ offs,
                                                    int* __restrict__ csr,
                                                    float* __restrict__ dinv,
                                                    int* __restrict__ degarr) {
    __shared__ int h[256];
    __shared__ int sc[256];
    __shared__ int cur[256];
    const int b = blockIdx.x, t = threadIdx.x;
    const int beg = bucket_base[b];
    const int end = bucket_base[b + 1];
    h[t] = 0;
    __syncthreads();
    for (int j = beg + t; j < end; j += 256) {
        int2 p = binned[j];
        atomicAdd(&h[p.y & 255], 1);
    }
    __syncthreads();
    int deg = h[t];
    sc[t] = deg;
    __syncthreads();
    for (int off = 1; off < 256; off <<= 1) {
        int v = (t >= off) ? sc[t - off] : 0;
        __syncthreads();
        sc[t] += v;
        __syncthreads();
    }
    int excl = sc[t] - deg;
    cur[t] = excl;
    int node = b * 256 + t;
    if (node < N_NODES) {
        offs[node] = beg + excl;
        dinv[node] = rsqrtf((float)deg + 1.0f);  // +1 self-loop
        degarr[node] = deg;
    }
    __syncthreads();
    for (int j = beg + t; j < end; j += 256) {
        int2 p = binned[j];
        int pos = atomicAdd(&cur[p.y & 255], 1);
        csr[beg + pos] = p.x;
    }
}

// ---------------- pack src|deg<<20 into csr in place (kills random dinv gather in inner loops) ----
__global__ __launch_bounds__(256) void pack_kernel(int* __restrict__ csr,
                                                   const int* __restrict__ degarr) {
    int i = blockIdx.x * 256 + threadIdx.x;
    if (i >= N_EDGES / 4) return;
    int4 c = ((int4*)csr)[i];
    c.x |= degarr[c.x] << 20;
    c.y |= degarr[c.y] << 20;
    c.z |= degarr[c.z] << 20;
    c.w |= degarr[c.w] << 20;
    ((int4*)csr)[i] = c;
}

// ---------------- gather aggregation, both 64-col half-tables in one launch ----------------
// blocks [0, 12500): half A; [12500, 25000): half B.
// 32 lanes/node = 4 sub-groups x 8 fl lanes; row = 64 bf16 = 128B = 8 uint4.
// 16 edges in flight; fully predicated; packed csr (src|deg<<20).
__global__ __launch_bounds__(256) void gather64(const ushort_t* __restrict__ h0a,
                                                const ushort_t* __restrict__ h0b,
                                                const int* __restrict__ offs,
                                                const int* __restrict__ csr,
                                                const float* __restrict__ dinv,
                                                ushort_t* __restrict__ aggA,
                                                ushort_t* __restrict__ aggB) {
    const int half = blockIdx.x >= (N_NODES / 8);
    const int nb = blockIdx.x - half * (N_NODES / 8);
    const ushort_t* tab = half ? h0b : h0a;
    ushort_t* outt = half ? aggB : aggA;

    const int node = nb * 8 + (threadIdx.x >> 5);
    const int l = threadIdx.x & 31;
    const int sub = l >> 3;        // 0..3
    const int fl = l & 7;          // 0..7
    const float dn = dinv[node];
    const uint4* rowbase = (const uint4*)tab;  // row = 8 uint4

    uint4 sv = rowbase[(size_t)node * 8 + fl];
    float s = (sub == 0) ? dn * dn : 0.f;
    float a[8];
    a[0] = bf_lo(sv.x) * s; a[1] = bf_hi(sv.x) * s;
    a[2] = bf_lo(sv.y) * s; a[3] = bf_hi(sv.y) * s;
    a[4] = bf_lo(sv.z) * s; a[5] = bf_hi(sv.z) * s;
    a[6] = bf_lo(sv.w) * s; a[7] = bf_hi(sv.w) * s;

    const int beg = offs[node], end = offs[node + 1];
    for (int j = beg; j < end; j += 16) {
        uint_t w[4];
        float nn[4];
        uint4 r[4];
#pragma unroll
        for (int k = 0; k < 4; k++) w[k] = ((const uint_t*)csr)[j + 4 * k + sub];
#pragma unroll
        for (int k = 0; k < 4; k++) {
            bool v = (j + 4 * k + sub) < end;
            int src = v ? (int)(w[k] & 0xFFFFFu) : 0;
            nn[k] = v ? rsqrtf((float)(w[k] >> 20) + 1.0f) * dn : 0.f;
            r[k] = rowbase[(size_t)src * 8 + fl];
        }
#pragma unroll
        for (int k = 0; k < 4; k++) {
            float n = nn[k];
            a[0] += bf_lo(r[k].x) * n; a[1] += bf_hi(r[k].x) * n;
            a[2] += bf_lo(r[k].y) * n; a[3] += bf_hi(r[k].y) * n;
            a[4] += bf_lo(r[k].z) * n; a[5] += bf_hi(r[k].z) * n;
            a[6] += bf_lo(r[k].w) * n; a[7] += bf_hi(r[k].w) * n;
        }
    }
    // reduce across the 4 sub-groups (lane xor 8, 16 stay within the 32-lane node group)
#pragma unroll
    for (int i = 0; i < 8; i++) {
        a[i] += __shfl_xor(a[i], 8);
        a[i] += __shfl_xor(a[i], 16);
    }
    if (sub == 0) {
        uint4 p;
        p.x = (uint_t)f2bf(a[0]) | ((uint_t)f2bf(a[1]) << 16);
        p.y = (uint_t)f2bf(a[2]) | ((uint_t)f2bf(a[3]) << 16);
        p.z = (uint_t)f2bf(a[4]) | ((uint_t)f2bf(a[5]) << 16);
        p.w = (uint_t)f2bf(a[6]) | ((uint_t)f2bf(a[7]) << 16);
        ((uint4*)outt)[(size_t)node * 8 + fl] = p;
    }
}

// ---------------- GEMM2 (MFMA): h2 = bf16(relu(agg + b1) @ W2), column-split input ----------------
__global__ __launch_bounds__(256) void gemm2_kernel(const ushort_t* __restrict__ aggA,
                                                    const ushort_t* __restrict__ aggB,
                                                    const float* __restrict__ b1,
                                                    const ushort_t* __restrict__ W2T,
                                                    ushort_t* __restrict__ h2bf) {
    __shared__ ushort_t Bs[F_OUT][F_HID + 8];  // 32 x 136 bf16 = 8.7 KB
    __shared__ float b1s[F_HID];
    const int tid = threadIdx.x;
    const int rbase = blockIdx.x * 64;
    const int w = tid >> 6;
    const int lane = tid & 63;
    const int q = lane >> 4;
    const int nloc = lane & 15;

    if (tid < F_HID) b1s[tid] = b1[tid];
#pragma unroll
    for (int jj = 0; jj < 2; jj++) {
        int f = jj * 256 + tid;       // 0..511
        int n = f >> 4, kg = f & 15;
        uint4 v = ((const uint4*)(W2T + n * F_HID))[kg];
        *(uint4*)(&Bs[n][kg * 8]) = v;
    }
    __syncthreads();

    const int rowA = rbase + w * 16 + nloc;
    const bool okA = rowA < N_NODES;

    floatx4 acc[2];
    acc[0] = (floatx4){0.f, 0.f, 0.f, 0.f};
    acc[1] = (floatx4){0.f, 0.f, 0.f, 0.f};

#pragma unroll
    for (int k0 = 0; k0 < F_HID; k0 += 32) {
        int kk = k0 + q * 8;          // k0 is unroll-constant; half select folds at compile time
        const ushort_t* at = (k0 < 64) ? aggA : aggB;
        int kloc = (k0 < 64) ? kk : kk - 64;
        uint4 av = make_uint4(0, 0, 0, 0);
        if (okA) av = *(const uint4*)(at + (size_t)rowA * 64 + kloc);
        float4 bb0 = *(const float4*)(&b1s[kk]);
        float4 bb1 = *(const float4*)(&b1s[kk + 4]);
        uint4 au;
        au.x = bfpack_trunc(fmaxf(bf_lo(av.x) + bb0.x, 0.f), fmaxf(bf_hi(av.x) + bb0.y, 0.f));
        au.y = bfpack_trunc(fmaxf(bf_lo(av.y) + bb0.z, 0.f), fmaxf(bf_hi(av.y) + bb0.w, 0.f));
        au.z = bfpack_trunc(fmaxf(bf_lo(av.z) + bb1.x, 0.f), fmaxf(bf_hi(av.z) + bb1.y, 0.f));
        au.w = bfpack_trunc(fmaxf(bf_lo(av.w) + bb1.z, 0.f), fmaxf(bf_hi(av.w) + bb1.w, 0.f));
        short8 a = *(short8*)&au;
#pragma unroll
        for (int t = 0; t < 2; t++) {
            short8 b = *(const short8*)(&Bs[t * 16 + nloc][kk]);
            acc[t] = __builtin_amdgcn_mfma_f32_16x16x32_bf16(a, b, acc[t], 0, 0, 0);
        }
    }
#pragma unroll
    for (int reg = 0; reg < 4; reg++) {
        int rowD = rbase + w * 16 + q * 4 + reg;
        if (rowD < N_NODES) {
            ushort_t* op = h2bf + (size_t)rowD * F_OUT + nloc;
            op[0]  = f2bf(acc[0][reg]);
            op[16] = f2bf(acc[1][reg]);
        }
    }
}

// ---------------- gather aggregation layer 2 + bias + log_softmax ----------------
// 32 lanes/node; 8 sub-groups x 4 lanes (uint4 = 16B/lane covers a 64B row with 4 lanes).
// 2 slots/iter = 16 edges in flight, fully predicated.
__global__ __launch_bounds__(256) void gather32_lsm(const ushort_t* __restrict__ h2bf,
                                                    const int* __restrict__ offs,
                                                    const int* __restrict__ csr,
                                                    const float* __restrict__ dinv,
                                                    const float* __restrict__ b2,
                                                    float* __restrict__ out) {
    const int node = blockIdx.x * 8 + (threadIdx.x >> 5);
    const int l = threadIdx.x & 31;
    const int sub = l >> 2;       // 0..7
    const int fl = l & 3;         // 0..3
    const float dn = dinv[node];
    const uint4* rowbase = (const uint4*)h2bf;  // row = 4 uint4

    uint4 sv = rowbase[(size_t)node * 4 + fl];
    float s = (sub == 0) ? dn * dn : 0.f;
    float a[8];
    a[0] = bf_lo(sv.x) * s; a[1] = bf_hi(sv.x) * s;
    a[2] = bf_lo(sv.y) * s; a[3] = bf_hi(sv.y) * s;
    a[4] = bf_lo(sv.z) * s; a[5] = bf_hi(sv.z) * s;
    a[6] = bf_lo(sv.w) * s; a[7] = bf_hi(sv.w) * s;

    const int beg = offs[node], end = offs[node + 1];
    for (int j = beg; j < end; j += 16) {
        uint_t w[2];
        float nn[2];
        uint4 r[2];
#pragma unroll
        for (int k = 0; k < 2; k++) w[k] = ((const uint_t*)csr)[j + 8 * k + sub];
#pragma unroll
        for (int k = 0; k < 2; k++) {
            bool v = (j + 8 * k + sub) < end;
            int src = v ? (int)(w[k] & 0xFFFFFu) : 0;
            nn[k] = v ? rsqrtf((float)(w[k] >> 20) + 1.0f) * dn : 0.f;
            r[k] = rowbase[(size_t)src * 4 + fl];
        }
#pragma unroll
        for (int k = 0; k < 2; k++) {
            float n = nn[k];
            a[0] += bf_lo(r[k].x) * n; a[1] += bf_hi(r[k].x) * n;
            a[2] += bf_lo(r[k].y) * n; a[3] += bf_hi(r[k].y) * n;
            a[4] += bf_lo(r[k].z) * n; a[5] += bf_hi(r[k].z) * n;
            a[6] += bf_lo(r[k].w) * n; a[7] += bf_hi(r[k].w) * n;
        }
    }
    // reduce across the 8 sub-groups
#pragma unroll
    for (int i = 0; i < 8; i++) {
        a[i] += __shfl_xor(a[i], 4);
        a[i] += __shfl_xor(a[i], 8);
        a[i] += __shfl_xor(a[i], 16);
    }
    // bias (after reduce!)
    float4 bb0 = ((const float4*)b2)[fl * 2];
    float4 bb1 = ((const float4*)b2)[fl * 2 + 1];
    a[0] += bb0.x; a[1] += bb0.y; a[2] += bb0.z; a[3] += bb0.w;
    a[4] += bb1.x; a[5] += bb1.y; a[6] += bb1.z; a[7] += bb1.w;

    // log_softmax across 32 cols (4 fl lanes x 8 regs)
    float m = a[0];
#pragma unroll
    for (int i = 1; i < 8; i++) m = fmaxf(m, a[i]);
    m = fmaxf(m, __shfl_xor(m, 1));
    m = fmaxf(m, __shfl_xor(m, 2));
    float es = 0.f;
#pragma unroll
    for (int i = 0; i < 8; i++) es += __expf(a[i] - m);
    es += __shfl_xor(es, 1);
    es += __shfl_xor(es, 2);
    float lse = m + __logf(es);

    if (sub == 0) {
        float4 o0 = make_float4(a[0] - lse, a[1] - lse, a[2] - lse, a[3] - lse);
        float4 o1 = make_float4(a[4] - lse, a[5] - lse, a[6] - lse, a[7] - lse);
        float4* op = (float4*)(out + (size_t)node * F_OUT);
        op[fl * 2] = o0;
        op[fl * 2 + 1] = o1;
    }
}

extern "C" void kernel_launch(void* const* d_in, const int* in_sizes, int n_in,
                              void* d_out, int out_size, void* d_ws, size_t ws_size,
                              hipStream_t stream) {
    const float* x  = (const float*)d_in[0];
    const int*   ei = (const int*)d_in[1];
    const float* W1 = (const float*)d_in[2];
    const float* b1 = (const float*)d_in[3];
    const float* W2 = (const float*)d_in[4];
    const float* b2 = (const float*)d_in[5];
    float* out = (float*)d_out;

    // workspace layout (4B units)
    float* ws = (float*)d_ws;
    float*    dinv          = ws;                      // 100096
    int*      offs          = (int*)(ws + 100096);     // 100128
    int*      bucket_cnt    = (int*)(ws + 200224);     // 512
    int*      bucket_base   = (int*)(ws + 200736);     // 512
    int*      bucket_cursor = (int*)(ws + 201248);     // 512
    int*      degarr        = (int*)(ws + 201760);     // 100096
    int*      csr           = (int*)(ws + 301856);     // 1,600,000 (16B aligned)
    ushort_t* W1T           = (ushort_t*)(ws + 1901856);   // 32768 ushort
    ushort_t* W2T           = (ushort_t*)(ws + 1918240);   // 4096 ushort
    ushort_t* h0a           = (ushort_t*)(ws + 1920288);   // 6.4M ushort (12.8 MB)
    ushort_t* h0b           = (ushort_t*)(ws + 5120288);   // 6.4M ushort
    ushort_t* aggA          = (ushort_t*)(ws + 8320288);   // 6.4M ushort
    ushort_t* aggB          = (ushort_t*)(ws + 11520288);  // 6.4M ushort
    ushort_t* h2bf          = (ushort_t*)(ws + 14720288);  // 3.2M ushort
    int2*     binned        = (int2*)aggA;                 // alias: 1.6M int2 = 12.8 MB, dead before gathers

    hipMemsetAsync(bucket_cnt, 0, 512 * sizeof(int), stream);
    histwt_kernel<<<BIN_BLOCKS + 32, 256, 0, stream>>>(ei, bucket_cnt, W1, W2, W1T, W2T);
    scan_kernel<<<1, 512, 0, stream>>>(bucket_cnt, bucket_base, bucket_cursor, offs);
    bin_gemm1_kernel<<<BIN_BLOCKS + G1_BLOCKS, 256, 0, stream>>>(ei, bucket_cursor, binned,
                                                                 x, W1T, h0a, h0b);
    build_kernel<<<NBUCK, 256, 0, stream>>>(binned, bucket_base, offs, csr, dinv, degarr);
    pack_kernel<<<(N_EDGES / 4 + 255) / 256, 256, 0, stream>>>(csr, degarr);
    gather64<<<2 * (N_NODES / 8), 256, 0, stream>>>(h0a, h0b, offs, csr, dinv, aggA, aggB);
    gemm2_kernel<<<(N_NODES + 63) / 64, 256, 0, stream>>>(aggA, aggB, b1, W2T, h2bf);
    gather32_lsm<<<N_NODES / 8, 256, 0, stream>>>(h2bf, offs, csr, dinv, b2, out);
}

// Round 8
// 334.025 us; speedup vs baseline: 1.1067x; 1.1067x over previous
//
#include <hip/hip_runtime.h>

#define N_NODES 100000
#define N_EDGES 1600000
#define F_IN 256
#define F_HID 128
#define F_OUT 32
#define NBUCK 391           // ceil(100000/256) buckets of 256 node ids
#define BIN_BLOCKS 512
#define EDGES_PER_BIN 3125  // 512*3125 = 1,600,000
#define G1_BLOCKS 1563      // ceil(100000/64) 64-row gemm1 tiles

typedef unsigned short ushort_t;
typedef unsigned int uint_t;

using short8  = __attribute__((ext_vector_type(8))) short;
using floatx4 = __attribute__((ext_vector_type(4))) float;

__device__ __forceinline__ ushort_t f2bf(float f) {
    uint_t u = __float_as_uint(f);
    u += 0x7fff + ((u >> 16) & 1);  // RNE
    return (ushort_t)(u >> 16);
}
__device__ __forceinline__ float bf_lo(uint_t u) { return __uint_as_float(u << 16); }
__device__ __forceinline__ float bf_hi(uint_t u) { return __uint_as_float(u & 0xffff0000u); }
// pack hi16(b):hi16(a) into one uint via v_perm_b32 (truncating bf16 x2, 1 instr)
__device__ __forceinline__ uint_t bfpack_trunc(float a, float b) {
    return __builtin_amdgcn_perm(__float_as_uint(b), __float_as_uint(a), 0x07060302u);
}

// ---------------- CSR pass 1 (blocks 0..511) + weight transpose (blocks 512..543) ----------------
__global__ __launch_bounds__(256) void histwt_kernel(const int* __restrict__ ei,
                                                     int* __restrict__ bucket_cnt,
                                                     const float* __restrict__ W1,
                                                     const float* __restrict__ W2,
                                                     ushort_t* __restrict__ W1T,
                                                     ushort_t* __restrict__ W2T) {
    __shared__ int h[NBUCK];
    if (blockIdx.x < BIN_BLOCKS) {
        for (int i = threadIdx.x; i < NBUCK; i += 256) h[i] = 0;
        __syncthreads();
        int gid = blockIdx.x * 256 + threadIdx.x;
        for (int e = gid; e < N_EDGES; e += BIN_BLOCKS * 256)
            atomicAdd(&h[ei[N_EDGES + e] >> 8], 1);
        __syncthreads();
        for (int i = threadIdx.x; i < NBUCK; i += 256) {
            int c = h[i];
            if (c) atomicAdd(&bucket_cnt[i], c);
        }
    } else {
        int t = (blockIdx.x - BIN_BLOCKS) * 256 + threadIdx.x;  // 0..8191
#pragma unroll
        for (int j = 0; j < 4; j++) {
            int e = j * 8192 + t;                // e = n*256 + k
            int n = e >> 8, k = e & 255;
            W1T[e] = f2bf(W1[k * F_HID + n]);
        }
        if (t < 4096) {
            int n = t >> 7, k = t & 127;
            W2T[t] = f2bf(W2[k * F_OUT + n]);
        }
    }
}

// ---------------- CSR build: scan bucket counts ----------------
__global__ __launch_bounds__(512) void scan_kernel(const int* __restrict__ bucket_cnt,
                                                   int* __restrict__ bucket_base,
                                                   int* __restrict__ bucket_cursor,
                                                   int* __restrict__ offs) {
    __shared__ int s[512];
    int t = threadIdx.x;
    int own = (t < NBUCK) ? bucket_cnt[t] : 0;
    s[t] = own;
    __syncthreads();
    for (int off = 1; off < 512; off <<= 1) {
        int v = (t >= off) ? s[t - off] : 0;
        __syncthreads();
        s[t] += v;
        __syncthreads();
    }
    if (t < NBUCK) {
        int ex = s[t] - own;
        bucket_base[t] = ex;
        bucket_cursor[t] = ex;
    }
    if (t == 0) {
        bucket_base[NBUCK] = N_EDGES;
        offs[N_NODES] = N_EDGES;
    }
}

// ---------------- fused: CSR bin (blocks 0..511) + GEMM1 (blocks 512..2074) ----------------
// bin part: bin edges into bucket regions (3.1 KB of the union).
// gemm1 part: h0 = bf16(x @ W1), 256 threads / 4 waves, 64-row tile, K-SPLIT LDS staging:
//   two passes over k (0..127, 128..255), each staging a [128][136] half-tile (34.8 KB).
//   34.8 KB (vs r6's 66 KB) -> 4 blocks/CU instead of 2: bin keeps latency-hiding waves,
//   gemm1 keeps LDS-fed MFMAs (r7 showed global-fed B serializes on vmcnt at VGPR=48).
//   Output column-split: cols 0..63 -> h0a[N][64], 64..127 -> h0b[N][64].
__global__ __launch_bounds__(256) void bin_gemm1_kernel(const int* __restrict__ ei,
                                                        int* __restrict__ bucket_cursor,
                                                        int2* __restrict__ binned,
                                                        const float* __restrict__ x,
                                                        const ushort_t* __restrict__ W1T,
                                                        ushort_t* __restrict__ h0a,
                                                        ushort_t* __restrict__ h0b) {
    __shared__ __align__(16) char smem[(size_t)F_HID * 136 * 2];  // 34816 B union
    const int tid = threadIdx.x;
    if (blockIdx.x < BIN_BLOCKS) {
        int* h    = (int*)smem;          // [NBUCK]
        int* base = ((int*)smem) + NBUCK;
        const int beg = blockIdx.x * EDGES_PER_BIN;
        const int end = beg + EDGES_PER_BIN;
        for (int i = tid; i < NBUCK; i += 256) h[i] = 0;
        __syncthreads();
        for (int e = beg + tid; e < end; e += 256) atomicAdd(&h[ei[N_EDGES + e] >> 8], 1);
        __syncthreads();
        for (int i = tid; i < NBUCK; i += 256) {
            int c = h[i];
            base[i] = c ? atomicAdd(&bucket_cursor[i], c) : 0;
            h[i] = 0;
        }
        __syncthreads();
        for (int e = beg + tid; e < end; e += 256) {
            int s = ei[e], d = ei[N_EDGES + e];
            int bk = d >> 8;
            int p = base[bk] + atomicAdd(&h[bk], 1);
            binned[p] = make_int2(s, d);
        }
    } else {
        ushort_t (*Bst)[136] = (ushort_t(*)[136])smem;  // 128 rows x 136 bf16 (one k-half)
        const int rbase = (blockIdx.x - BIN_BLOCKS) * 64;
        const int w = tid >> 6;        // wave 0..3
        const int lane = tid & 63;
        const int q = lane >> 4;       // quad 0..3
        const int nloc = lane & 15;    // 0..15

        const int rowA = rbase + w * 16 + nloc;
        const bool okA = rowA < N_NODES;
        const float* ap = x + (size_t)rowA * F_IN + q * 8;

        floatx4 acc[8];
#pragma unroll
        for (int t = 0; t < 8; t++) acc[t] = (floatx4){0.f, 0.f, 0.f, 0.f};

#pragma unroll
        for (int half = 0; half < 2; half++) {
            // stage W1T[:, half*128 .. half*128+127] -> Bst (2048 x 16B, 8 per thread)
#pragma unroll
            for (int j = 0; j < 8; j++) {
                int f = j * 256 + tid;           // 0..2047
                int n = f >> 4, kg = f & 15;     // row 0..127, 8-bf16 chunk 0..15
                uint4 v = ((const uint4*)(W1T + n * F_IN + half * 128))[kg];
                *(uint4*)(&Bst[n][kg * 8]) = v;
            }
            __syncthreads();

#pragma unroll
            for (int k0 = 0; k0 < 128; k0 += 32) {
                float4 f0 = make_float4(0.f, 0.f, 0.f, 0.f);
                float4 f1 = make_float4(0.f, 0.f, 0.f, 0.f);
                if (okA) {
                    f0 = *(const float4*)(ap + half * 128 + k0);
                    f1 = *(const float4*)(ap + half * 128 + k0 + 4);
                }
                uint4 au;
                au.x = bfpack_trunc(f0.x, f0.y);
                au.y = bfpack_trunc(f0.z, f0.w);
                au.z = bfpack_trunc(f1.x, f1.y);
                au.w = bfpack_trunc(f1.z, f1.w);
                short8 a = *(short8*)&au;
#pragma unroll
                for (int t = 0; t < 8; t++) {
                    short8 b = *(const short8*)(&Bst[t * 16 + nloc][k0 + q * 8]);
                    acc[t] = __builtin_amdgcn_mfma_f32_16x16x32_bf16(a, b, acc[t], 0, 0, 0);
                }
            }
            __syncthreads();  // all reads done before next half's restage
        }

        // D layout: col = lane&15 (n within tile), row = q*4 + reg
#pragma unroll
        for (int reg = 0; reg < 4; reg++) {
            int rowD = rbase + w * 16 + q * 4 + reg;
            if (rowD < N_NODES) {
                ushort_t* opA = h0a + (size_t)rowD * 64 + nloc;
                ushort_t* opB = h0b + (size_t)rowD * 64 + nloc;
#pragma unroll
                for (int t = 0; t < 4; t++) opA[t * 16] = f2bf(acc[t][reg]);
#pragma unroll
                for (int t = 4; t < 8; t++) opB[(t - 4) * 16] = f2bf(acc[t][reg]);
            }
        }
    }
}

// ---------------- CSR build, pass 3: per-bucket offs/dinv/deg/csr ----------------
__global__ __launch_bounds__(256) void build_kernel(const int2* __restrict__ binned,
                                                    const int* __restrict__ bucket_base,
                                                    int* __restrict__ offs,
                                                    int* __restrict__ csr,
                                                    float* __restrict__ dinv,
                                                    int* __restrict__ degarr) {
    __shared__ int h[256];
    __shared__ int sc[256];
    __shared__ int cur[256];
    const int b = blockIdx.x, t = threadIdx.x;
    const int beg = bucket_base[b];
    const int end = bucket_base[b + 1];
    h[t] = 0;
    __syncthreads();
    for (int j = beg + t; j < end; j += 256) {
        int2 p = binned[j];
        atomicAdd(&h[p.y & 255], 1);
    }
    __syncthreads();
    int deg = h[t];
    sc[t] = deg;
    __syncthreads();
    for (int off = 1; off < 256; off <<= 1) {
        int v = (t >= off) ? sc[t - off] : 0;
        __syncthreads();
        sc[t] += v;
        __syncthreads();
    }
    int excl = sc[t] - deg;
    cur[t] = excl;
    int node = b * 256 + t;
    if (node < N_NODES) {
        offs[node] = beg + excl;
        dinv[node] = rsqrtf((float)deg + 1.0f);  // +1 self-loop
        degarr[node] = deg;
    }
    __syncthreads();
    for (int j = beg + t; j < end; j += 256) {
        int2 p = binned[j];
        int pos = atomicAdd(&cur[p.y & 255], 1);
        csr[beg + pos] = p.x;
    }
}

// ---------------- pack src|deg<<20 into csr in place (kills random dinv gather in inner loops) ----
__global__ __launch_bounds__(256) void pack_kernel(int* __restrict__ csr,
                                                   const int* __restrict__ degarr) {
    int i = blockIdx.x * 256 + threadIdx.x;
    if (i >= N_EDGES / 4) return;
    int4 c = ((int4*)csr)[i];
    c.x |= degarr[c.x] << 20;
    c.y |= degarr[c.y] << 20;
    c.z |= degarr[c.z] << 20;
    c.w |= degarr[c.w] << 20;
    ((int4*)csr)[i] = c;
}

// ---------------- gather aggregation, both 64-col half-tables in one launch ----------------
// blocks [0, 12500): half A; [12500, 25000): half B.
// 32 lanes/node = 4 sub-groups x 8 fl lanes; row = 64 bf16 = 128B = 8 uint4.
// 16 edges in flight; fully predicated; packed csr (src|deg<<20).
__global__ __launch_bounds__(256) void gather64(const ushort_t* __restrict__ h0a,
                                                const ushort_t* __restrict__ h0b,
                                                const int* __restrict__ offs,
                                                const int* __restrict__ csr,
                                                const float* __restrict__ dinv,
                                                ushort_t* __restrict__ aggA,
                                                ushort_t* __restrict__ aggB) {
    const int half = blockIdx.x >= (N_NODES / 8);
    const int nb = blockIdx.x - half * (N_NODES / 8);
    const ushort_t* tab = half ? h0b : h0a;
    ushort_t* outt = half ? aggB : aggA;

    const int node = nb * 8 + (threadIdx.x >> 5);
    const int l = threadIdx.x & 31;
    const int sub = l >> 3;        // 0..3
    const int fl = l & 7;          // 0..7
    const float dn = dinv[node];
    const uint4* rowbase = (const uint4*)tab;  // row = 8 uint4

    uint4 sv = rowbase[(size_t)node * 8 + fl];
    float s = (sub == 0) ? dn * dn : 0.f;
    float a[8];
    a[0] = bf_lo(sv.x) * s; a[1] = bf_hi(sv.x) * s;
    a[2] = bf_lo(sv.y) * s; a[3] = bf_hi(sv.y) * s;
    a[4] = bf_lo(sv.z) * s; a[5] = bf_hi(sv.z) * s;
    a[6] = bf_lo(sv.w) * s; a[7] = bf_hi(sv.w) * s;

    const int beg = offs[node], end = offs[node + 1];
    for (int j = beg; j < end; j += 16) {
        uint_t w[4];
        float nn[4];
        uint4 r[4];
#pragma unroll
        for (int k = 0; k < 4; k++) w[k] = ((const uint_t*)csr)[j + 4 * k + sub];
#pragma unroll
        for (int k = 0; k < 4; k++) {
            bool v = (j + 4 * k + sub) < end;
            int src = v ? (int)(w[k] & 0xFFFFFu) : 0;
            nn[k] = v ? rsqrtf((float)(w[k] >> 20) + 1.0f) * dn : 0.f;
            r[k] = rowbase[(size_t)src * 8 + fl];
        }
#pragma unroll
        for (int k = 0; k < 4; k++) {
            float n = nn[k];
            a[0] += bf_lo(r[k].x) * n; a[1] += bf_hi(r[k].x) * n;
            a[2] += bf_lo(r[k].y) * n; a[3] += bf_hi(r[k].y) * n;
            a[4] += bf_lo(r[k].z) * n; a[5] += bf_hi(r[k].z) * n;
            a[6] += bf_lo(r[k].w) * n; a[7] += bf_hi(r[k].w) * n;
        }
    }
    // reduce across the 4 sub-groups (lane xor 8, 16 stay within the 32-lane node group)
#pragma unroll
    for (int i = 0; i < 8; i++) {
        a[i] += __shfl_xor(a[i], 8);
        a[i] += __shfl_xor(a[i], 16);
    }
    if (sub == 0) {
        uint4 p;
        p.x = (uint_t)f2bf(a[0]) | ((uint_t)f2bf(a[1]) << 16);
        p.y = (uint_t)f2bf(a[2]) | ((uint_t)f2bf(a[3]) << 16);
        p.z = (uint_t)f2bf(a[4]) | ((uint_t)f2bf(a[5]) << 16);
        p.w = (uint_t)f2bf(a[6]) | ((uint_t)f2bf(a[7]) << 16);
        ((uint4*)outt)[(size_t)node * 8 + fl] = p;
    }
}

// ---------------- GEMM2 (MFMA): h2 = bf16(relu(agg + b1) @ W2), column-split input ----------------
__global__ __launch_bounds__(256) void gemm2_kernel(const ushort_t* __restrict__ aggA,
                                                    const ushort_t* __restrict__ aggB,
                                                    const float* __restrict__ b1,
                                                    const ushort_t* __restrict__ W2T,
                                                    ushort_t* __restrict__ h2bf) {
    __shared__ ushort_t Bs[F_OUT][F_HID + 8];  // 32 x 136 bf16 = 8.7 KB
    __shared__ float b1s[F_HID];
    const int tid = threadIdx.x;
    const int rbase = blockIdx.x * 64;
    const int w = tid >> 6;
    const int lane = tid & 63;
    const int q = lane >> 4;
    const int nloc = lane & 15;

    if (tid < F_HID) b1s[tid] = b1[tid];
#pragma unroll
    for (int jj = 0; jj < 2; jj++) {
        int f = jj * 256 + tid;       // 0..511
        int n = f >> 4, kg = f & 15;
        uint4 v = ((const uint4*)(W2T + n * F_HID))[kg];
        *(uint4*)(&Bs[n][kg * 8]) = v;
    }
    __syncthreads();

    const int rowA = rbase + w * 16 + nloc;
    const bool okA = rowA < N_NODES;

    floatx4 acc[2];
    acc[0] = (floatx4){0.f, 0.f, 0.f, 0.f};
    acc[1] = (floatx4){0.f, 0.f, 0.f, 0.f};

#pragma unroll
    for (int k0 = 0; k0 < F_HID; k0 += 32) {
        int kk = k0 + q * 8;          // k0 is unroll-constant; half select folds at compile time
        const ushort_t* at = (k0 < 64) ? aggA : aggB;
        int kloc = (k0 < 64) ? kk : kk - 64;
        uint4 av = make_uint4(0, 0, 0, 0);
        if (okA) av = *(const uint4*)(at + (size_t)rowA * 64 + kloc);
        float4 bb0 = *(const float4*)(&b1s[kk]);
        float4 bb1 = *(const float4*)(&b1s[kk + 4]);
        uint4 au;
        au.x = bfpack_trunc(fmaxf(bf_lo(av.x) + bb0.x, 0.f), fmaxf(bf_hi(av.x) + bb0.y, 0.f));
        au.y = bfpack_trunc(fmaxf(bf_lo(av.y) + bb0.z, 0.f), fmaxf(bf_hi(av.y) + bb0.w, 0.f));
        au.z = bfpack_trunc(fmaxf(bf_lo(av.z) + bb1.x, 0.f), fmaxf(bf_hi(av.z) + bb1.y, 0.f));
        au.w = bfpack_trunc(fmaxf(bf_lo(av.w) + bb1.z, 0.f), fmaxf(bf_hi(av.w) + bb1.w, 0.f));
        short8 a = *(short8*)&au;
#pragma unroll
        for (int t = 0; t < 2; t++) {
            short8 b = *(const short8*)(&Bs[t * 16 + nloc][kk]);
            acc[t] = __builtin_amdgcn_mfma_f32_16x16x32_bf16(a, b, acc[t], 0, 0, 0);
        }
    }
#pragma unroll
    for (int reg = 0; reg < 4; reg++) {
        int rowD = rbase + w * 16 + q * 4 + reg;
        if (rowD < N_NODES) {
            ushort_t* op = h2bf + (size_t)rowD * F_OUT + nloc;
            op[0]  = f2bf(acc[0][reg]);
            op[16] = f2bf(acc[1][reg]);
        }
    }
}

// ---------------- gather aggregation layer 2 + bias + log_softmax ----------------
// 32 lanes/node; 8 sub-groups x 4 lanes (uint4 = 16B/lane covers a 64B row with 4 lanes).
// 2 slots/iter = 16 edges in flight, fully predicated.
__global__ __launch_bounds__(256) void gather32_lsm(const ushort_t* __restrict__ h2bf,
                                                    const int* __restrict__ offs,
                                                    const int* __restrict__ csr,
                                                    const float* __restrict__ dinv,
                                                    const float* __restrict__ b2,
                                                    float* __restrict__ out) {
    const int node = blockIdx.x * 8 + (threadIdx.x >> 5);
    const int l = threadIdx.x & 31;
    const int sub = l >> 2;       // 0..7
    const int fl = l & 3;         // 0..3
    const float dn = dinv[node];
    const uint4* rowbase = (const uint4*)h2bf;  // row = 4 uint4

    uint4 sv = rowbase[(size_t)node * 4 + fl];
    float s = (sub == 0) ? dn * dn : 0.f;
    float a[8];
    a[0] = bf_lo(sv.x) * s; a[1] = bf_hi(sv.x) * s;
    a[2] = bf_lo(sv.y) * s; a[3] = bf_hi(sv.y) * s;
    a[4] = bf_lo(sv.z) * s; a[5] = bf_hi(sv.z) * s;
    a[6] = bf_lo(sv.w) * s; a[7] = bf_hi(sv.w) * s;

    const int beg = offs[node], end = offs[node + 1];
    for (int j = beg; j < end; j += 16) {
        uint_t w[2];
        float nn[2];
        uint4 r[2];
#pragma unroll
        for (int k = 0; k < 2; k++) w[k] = ((const uint_t*)csr)[j + 8 * k + sub];
#pragma unroll
        for (int k = 0; k < 2; k++) {
            bool v = (j + 8 * k + sub) < end;
            int src = v ? (int)(w[k] & 0xFFFFFu) : 0;
            nn[k] = v ? rsqrtf((float)(w[k] >> 20) + 1.0f) * dn : 0.f;
            r[k] = rowbase[(size_t)src * 4 + fl];
        }
#pragma unroll
        for (int k = 0; k < 2; k++) {
            float n = nn[k];
            a[0] += bf_lo(r[k].x) * n; a[1] += bf_hi(r[k].x) * n;
            a[2] += bf_lo(r[k].y) * n; a[3] += bf_hi(r[k].y) * n;
            a[4] += bf_lo(r[k].z) * n; a[5] += bf_hi(r[k].z) * n;
            a[6] += bf_lo(r[k].w) * n; a[7] += bf_hi(r[k].w) * n;
        }
    }
    // reduce across the 8 sub-groups
#pragma unroll
    for (int i = 0; i < 8; i++) {
        a[i] += __shfl_xor(a[i], 4);
        a[i] += __shfl_xor(a[i], 8);
        a[i] += __shfl_xor(a[i], 16);
    }
    // bias (after reduce!)
    float4 bb0 = ((const float4*)b2)[fl * 2];
    float4 bb1 = ((const float4*)b2)[fl * 2 + 1];
    a[0] += bb0.x; a[1] += bb0.y; a[2] += bb0.z; a[3] += bb0.w;
    a[4] += bb1.x; a[5] += bb1.y; a[6] += bb1.z; a[7] += bb1.w;

    // log_softmax across 32 cols (4 fl lanes x 8 regs)
    float m = a[0];
#pragma unroll
    for (int i = 1; i < 8; i++) m = fmaxf(m, a[i]);
    m = fmaxf(m, __shfl_xor(m, 1));
    m = fmaxf(m, __shfl_xor(m, 2));
    float es = 0.f;
#pragma unroll
    for (int i = 0; i < 8; i++) es += __expf(a[i] - m);
    es += __shfl_xor(es, 1);
    es += __shfl_xor(es, 2);
    float lse = m + __logf(es);

    if (sub == 0) {
        float4 o0 = make_float4(a[0] - lse, a[1] - lse, a[2] - lse, a[3] - lse);
        float4 o1 = make_float4(a[4] - lse, a[5] - lse, a[6] - lse, a[7] - lse);
        float4* op = (float4*)(out + (size_t)node * F_OUT);
        op[fl * 2] = o0;
        op[fl * 2 + 1] = o1;
    }
}

extern "C" void kernel_launch(void* const* d_in, const int* in_sizes, int n_in,
                              void* d_out, int out_size, void* d_ws, size_t ws_size,
                              hipStream_t stream) {
    const float* x  = (const float*)d_in[0];
    const int*   ei = (const int*)d_in[1];
    const float* W1 = (const float*)d_in[2];
    const float* b1 = (const float*)d_in[3];
    const float* W2 = (const float*)d_in[4];
    const float* b2 = (const float*)d_in[5];
    float* out = (float*)d_out;

    // workspace layout (4B units)
    float* ws = (float*)d_ws;
    float*    dinv          = ws;                      // 100096
    int*      offs          = (int*)(ws + 100096);     // 100128
    int*      bucket_cnt    = (int*)(ws + 200224);     // 512
    int*      bucket_base   = (int*)(ws + 200736);     // 512
    int*      bucket_cursor = (int*)(ws + 201248);     // 512
    int*      degarr        = (int*)(ws + 201760);     // 100096
    int*      csr           = (int*)(ws + 301856);     // 1,600,000 (16B aligned)
    ushort_t* W1T           = (ushort_t*)(ws + 1901856);   // 32768 ushort
    ushort_t* W2T           = (ushort_t*)(ws + 1918240);   // 4096 ushort
    ushort_t* h0a           = (ushort_t*)(ws + 1920288);   // 6.4M ushort (12.8 MB)
    ushort_t* h0b           = (ushort_t*)(ws + 5120288);   // 6.4M ushort
    ushort_t* aggA          = (ushort_t*)(ws + 8320288);   // 6.4M ushort
    ushort_t* aggB          = (ushort_t*)(ws + 11520288);  // 6.4M ushort
    ushort_t* h2bf          = (ushort_t*)(ws + 14720288);  // 3.2M ushort
    int2*     binned        = (int2*)aggA;                 // alias: 1.6M int2 = 12.8 MB, dead before gathers

    hipMemsetAsync(bucket_cnt, 0, 512 * sizeof(int), stream);
    histwt_kernel<<<BIN_BLOCKS + 32, 256, 0, stream>>>(ei, bucket_cnt, W1, W2, W1T, W2T);
    scan_kernel<<<1, 512, 0, stream>>>(bucket_cnt, bucket_base, bucket_cursor, offs);
    bin_gemm1_kernel<<<BIN_BLOCKS + G1_BLOCKS, 256, 0, stream>>>(ei, bucket_cursor, binned,
                                                                 x, W1T, h0a, h0b);
    build_kernel<<<NBUCK, 256, 0, stream>>>(binned, bucket_base, offs, csr, dinv, degarr);
    pack_kernel<<<(N_EDGES / 4 + 255) / 256, 256, 0, stream>>>(csr, degarr);
    gather64<<<2 * (N_NODES / 8), 256, 0, stream>>>(h0a, h0b, offs, csr, dinv, aggA, aggB);
    gemm2_kernel<<<(N_NODES + 63) / 64, 256, 0, stream>>>(aggA, aggB, b1, W2T, h2bf);
    gather32_lsm<<<N_NODES / 8, 256, 0, stream>>>(h2bf, offs, csr, dinv, b2, out);
}